// Round 7
// baseline (227.910 us; speedup 1.0000x reference)
//
#include <hip/hip_runtime.h>
#include <math.h>

#define N_REL  8
#define IN_CH  16
#define HID_CH 32
#define OUT_CH 2

#define BIN_BITS  9
#define BIN_NODES 512                    // nodes per coarse bin
#define KPB       (BIN_NODES * N_REL)    // 4096 (node,rel) keys per bin
#define NCHUNK    192                    // partition chunks (blocks)

// ---------------------------------------------------------------------------
// B1a: per-chunk histogram over coarse bins (LDS), H[bin][chunk] (bin-major)
// ---------------------------------------------------------------------------
__global__ __launch_bounds__(256) void part_hist_kernel(const int* __restrict__ dst,
                                                        int* __restrict__ H,
                                                        int E, int nbins, int chunksz) {
    __shared__ int hist[256];
    int chunk = blockIdx.x;
    int e0 = chunk * chunksz;
    int e1 = e0 + chunksz; if (e1 > E) e1 = E;

    for (int i = threadIdx.x; i < nbins; i += 256) hist[i] = 0;
    __syncthreads();
    for (int e = e0 + threadIdx.x; e < e1; e += 256)
        atomicAdd(&hist[dst[e] >> BIN_BITS], 1);
    __syncthreads();
    for (int i = threadIdx.x; i < nbins; i += 256)
        H[i * NCHUNK + chunk] = hist[i];
}

// ---------------------------------------------------------------------------
// scan_a/b/c: exclusive scan of H[0..M2) in place
// ---------------------------------------------------------------------------
__global__ __launch_bounds__(1024) void scan_a_kernel(int* __restrict__ ptr,
                                                      int* __restrict__ blksum, int M) {
    int i = blockIdx.x * 1024 + threadIdx.x;
    int val = (i < M) ? ptr[i] : 0;
    int lane = threadIdx.x & 63;
    int wid  = threadIdx.x >> 6;

    int v = val;
#pragma unroll
    for (int off = 1; off < 64; off <<= 1) {
        int u = __shfl_up(v, off, 64);
        if (lane >= off) v += u;
    }

    __shared__ int wsum[16];
    if (lane == 63) wsum[wid] = v;
    __syncthreads();

    if (wid == 0) {
        int worig = (lane < 16) ? wsum[lane] : 0;
        int wv = worig;
#pragma unroll
        for (int off = 1; off < 16; off <<= 1) {
            int u = __shfl_up(wv, off, 64);
            if (lane >= off) wv += u;
        }
        if (lane < 16) wsum[lane] = wv - worig;
        if (lane == 15) blksum[blockIdx.x] = wv;
    }
    __syncthreads();

    if (i < M) ptr[i] = (v - val) + wsum[wid];
}

__global__ void scan_b_kernel(int* __restrict__ blksum, int nb) {
    int lane = threadIdx.x & 63;
    int run = 0;
    for (int base = 0; base < nb; base += 64) {
        int i = base + lane;
        int val = (i < nb) ? blksum[i] : 0;
        int v = val;
#pragma unroll
        for (int off = 1; off < 64; off <<= 1) {
            int u = __shfl_up(v, off, 64);
            if (lane >= off) v += u;
        }
        if (i < nb) blksum[i] = run + (v - val);
        run += __shfl(v, 63, 64);
    }
}

__global__ __launch_bounds__(1024) void scan_c_kernel(int* __restrict__ ptr,
                                                      const int* __restrict__ blksum, int M) {
    int i = blockIdx.x * 1024 + threadIdx.x;
    if (i < M) ptr[i] += blksum[blockIdx.x];
}

// ---------------------------------------------------------------------------
// B1b: partition — chunk-block writes packed records to per-(bin,chunk) runs.
// pack: (localdst<<20) | (rel<<17) | src   (src < 2^17, localdst < 512)
// ---------------------------------------------------------------------------
__global__ __launch_bounds__(256) void part_scatter_kernel(const int* __restrict__ src,
                                                           const int* __restrict__ dst,
                                                           const int* __restrict__ rel,
                                                           const int* __restrict__ Hs,
                                                           int* __restrict__ be,
                                                           int E, int nbins, int chunksz) {
    __shared__ int base[256];
    __shared__ int fil[256];
    int chunk = blockIdx.x;
    int e0 = chunk * chunksz;
    int e1 = e0 + chunksz; if (e1 > E) e1 = E;

    for (int i = threadIdx.x; i < nbins; i += 256) {
        base[i] = Hs[i * NCHUNK + chunk];
        fil[i]  = 0;
    }
    __syncthreads();

    for (int e = e0 + threadIdx.x; e < e1; e += 256) {
        int d = dst[e];
        int b = d >> BIN_BITS;
        int slot = base[b] + atomicAdd(&fil[b], 1);
        be[slot] = ((d & (BIN_NODES - 1)) << 20) | (rel[e] << 17) | src[e];
    }
}

// ---------------------------------------------------------------------------
// B2: one block per bin — LDS counting sort over 4096 keys -> ends[] + csr[].
// ---------------------------------------------------------------------------
__global__ __launch_bounds__(256) void bin_build_kernel(const int* __restrict__ be,
                                                        const int* __restrict__ Hs,
                                                        int* __restrict__ ends,
                                                        int* __restrict__ csr,
                                                        int E, int nbins) {
    int b  = blockIdx.x;
    int s0 = Hs[b * NCHUNK];
    int s1 = (b + 1 < nbins) ? Hs[(b + 1) * NCHUNK] : E;
    int t  = threadIdx.x;

    __shared__ int cnt[KPB];
    __shared__ int off[KPB];
    __shared__ int fil[KPB];
    __shared__ int ws[4];

    for (int i = t; i < KPB; i += 256) { cnt[i] = 0; fil[i] = 0; }
    __syncthreads();

    for (int p = s0 + t; p < s1; p += 256)
        atomicAdd(&cnt[be[p] >> 17], 1);          // key = (localdst<<3)|rel
    __syncthreads();

    int kbase = t * 16;
    int loc[16];
    int sum = 0;
#pragma unroll
    for (int i = 0; i < 16; ++i) { loc[i] = sum; sum += cnt[kbase + i]; }

    int lane = t & 63, wid = t >> 6;
    int v = sum;
#pragma unroll
    for (int o = 1; o < 64; o <<= 1) {
        int u = __shfl_up(v, o, 64);
        if (lane >= o) v += u;
    }
    if (lane == 63) ws[wid] = v;
    __syncthreads();
    int woff = 0;
    for (int i = 0; i < wid; ++i) woff += ws[i];
    int excl = woff + (v - sum);
#pragma unroll
    for (int i = 0; i < 16; ++i) off[kbase + i] = excl + loc[i];
    __syncthreads();

    for (int i = t; i < KPB; i += 256)
        ends[b * KPB + i] = s0 + off[i] + cnt[i];

    for (int p = s0 + t; p < s1; p += 256) {
        int pk = be[p];
        int k  = pk >> 17;
        int slot = s0 + off[k] + atomicAdd(&fil[k], 1);
        csr[slot] = pk & 0x1FFFF;
    }
}

// ---------------------------------------------------------------------------
// l1 fused aggregate-then-transform: half-wave per node, lane = channel c.
// Per (node,r) segment: lanes 0-15 sum x[src][f] over even edges, lanes 16-31
// over odd edges (gathers hit the 6.4MB L2-resident x, not a 51MB table);
// pair-combine via shfl_xor; rank-16 update against LDS weights; scale 1/len.
// ---------------------------------------------------------------------------
__global__ __launch_bounds__(256) void l1_fused_kernel(const float* __restrict__ x,
                                                       const int* __restrict__ csr,
                                                       const int* __restrict__ ends,
                                                       const float* __restrict__ W1,
                                                       const float* __restrict__ root1,
                                                       const float* __restrict__ b1,
                                                       float* __restrict__ h, int N) {
    __shared__ float sW[N_REL * IN_CH * HID_CH];   // 16 KB, native [r][f][c]
    for (int i = threadIdx.x; i < N_REL * IN_CH * HID_CH; i += 256)
        sW[i] = W1[i];
    __syncthreads();

    int gid  = blockIdx.x * 256 + threadIdx.x;
    int node = gid >> 5;
    int c    = gid & 31;
    if (node >= N) return;
    int f   = c & 15;       // input-feature slot this lane aggregates
    int sub = c >> 4;       // edge parity this lane loads

    int4 e0 = ((const int4*)ends)[node * 2];
    int4 e1 = ((const int4*)ends)[node * 2 + 1];
    int end_r[N_REL] = {e0.x, e0.y, e0.z, e0.w, e1.x, e1.y, e1.z, e1.w};

    int prev = (node > 0) ? __ldg(&ends[node * N_REL - 1]) : 0;
    float acc = 0.0f;

    for (int r = 0; r < N_REL; ++r) {
        int end = end_r[r];
        int len = end - prev;
        if (len > 0) {
            float ax = 0.0f;
            for (int p = prev + sub; p < end; p += 2)
                ax += x[(csr[p] << 4) + f];
            float axp = ax + __shfl_xor(ax, 16, 32);   // full per-f segment sum
            const float* wr = sW + (r << 9) + c;
            float seg = 0.0f;
#pragma unroll
            for (int ff = 0; ff < 16; ++ff)
                seg = fmaf(__shfl(axp, ff, 32), wr[ff << 5], seg);
            acc = fmaf(seg, 1.0f / (float)len, acc);
            prev = end;
        }
    }

    // root term + bias + relu
    const float4* xs = (const float4*)(x + ((long)node << 4));
    float4 v0 = xs[0], v1 = xs[1], v2 = xs[2], v3 = xs[3];
    const float* wr = root1 + c;
    acc += b1[c];
    acc += v0.x * wr[0]   + v0.y * wr[32]  + v0.z * wr[64]  + v0.w * wr[96];
    acc += v1.x * wr[128] + v1.y * wr[160] + v1.z * wr[192] + v1.w * wr[224];
    acc += v2.x * wr[256] + v2.y * wr[288] + v2.z * wr[320] + v2.w * wr[352];
    acc += v3.x * wr[384] + v3.y * wr[416] + v3.z * wr[448] + v3.w * wr[480];
    h[(node << 5) + c] = fmaxf(acc, 0.0f);
}

// ---------------------------------------------------------------------------
// hw: hW[n][r][o] = h[n] @ W2[r][:,o];  hroot[n][o] = h[n]@root2[:,o] + b2[o]
// ---------------------------------------------------------------------------
__global__ __launch_bounds__(256) void hw_kernel(const float* __restrict__ h,
                                                 const float* __restrict__ W2,
                                                 const float* __restrict__ root2,
                                                 const float* __restrict__ b2,
                                                 float* __restrict__ hW,
                                                 float* __restrict__ hroot, int N) {
    int gid = blockIdx.x * 256 + threadIdx.x;
    if (gid >= N * 9) return;
    int n = gid / 9;
    int j = gid - n * 9;

    const float* hn = h + ((long)n << 5);
    const float* wp = (j < 8) ? (W2 + j * (HID_CH * OUT_CH)) : root2;

    float o0 = 0.0f, o1 = 0.0f;
#pragma unroll
    for (int f = 0; f < HID_CH; ++f) {
        float hf = hn[f];
        o0 += hf * wp[f * 2 + 0];
        o1 += hf * wp[f * 2 + 1];
    }
    if (j < 8) {
        *(float2*)(hW + ((long)n << 4) + (j << 1)) = make_float2(o0, o1);
    } else {
        *(float2*)(hroot + ((long)n << 1)) = make_float2(o0 + b2[0], o1 + b2[1]);
    }
}

// ---------------------------------------------------------------------------
// l2 finish: 8 lanes per node, lane = relation
// ---------------------------------------------------------------------------
__global__ __launch_bounds__(256) void l2_finish_kernel(const int* __restrict__ csr,
                                                        const int* __restrict__ ends,
                                                        const float* __restrict__ hW,
                                                        const float* __restrict__ hroot,
                                                        float* __restrict__ out, int N) {
    int gid  = blockIdx.x * 256 + threadIdx.x;
    int node = gid >> 3;
    int r    = gid & 7;
    if (node >= N) return;

    int idx  = node * N_REL + r;
    int prev = (idx > 0) ? ends[idx - 1] : 0;
    int end  = ends[idx];

    float o0 = 0.0f, o1 = 0.0f;
    if (end > prev) {
        float s0 = 0.0f, s1 = 0.0f;
        int p = prev;
        for (; p + 1 < end; p += 2) {
            int a = csr[p], b = csr[p + 1];
            float2 va = *(const float2*)(hW + ((long)a << 4) + (r << 1));
            float2 vb = *(const float2*)(hW + ((long)b << 4) + (r << 1));
            s0 += va.x + vb.x; s1 += va.y + vb.y;
        }
        if (p < end) {
            int a = csr[p];
            float2 va = *(const float2*)(hW + ((long)a << 4) + (r << 1));
            s0 += va.x; s1 += va.y;
        }
        float inv = 1.0f / (float)(end - prev);
        o0 = s0 * inv; o1 = s1 * inv;
    }

#pragma unroll
    for (int m = 1; m < 8; m <<= 1) {
        o0 += __shfl_xor(o0, m, 64);
        o1 += __shfl_xor(o1, m, 64);
    }

    if (r == 0) {
        float2 rt = *(const float2*)(hroot + ((long)node << 1));
        o0 += rt.x; o1 += rt.y;
        float mx = fmaxf(o0, o1);
        float l  = mx + logf(__expf(o0 - mx) + __expf(o1 - mx));
        *(float2*)(out + ((long)node << 1)) = make_float2(o0 - l, o1 - l);
    }
}

// ---------------------------------------------------------------------------
extern "C" void kernel_launch(void* const* d_in, const int* in_sizes, int n_in,
                              void* d_out, int out_size, void* d_ws, size_t ws_size,
                              hipStream_t stream) {
    const float* x     = (const float*)d_in[0];
    const int*   eidx  = (const int*)d_in[1];
    const int*   etype = (const int*)d_in[2];
    const float* W1    = (const float*)d_in[3];
    const float* root1 = (const float*)d_in[4];
    const float* b1    = (const float*)d_in[5];
    const float* W2    = (const float*)d_in[6];
    const float* root2 = (const float*)d_in[7];
    const float* b2    = (const float*)d_in[8];
    float* out = (float*)d_out;

    const int N = in_sizes[0] / IN_CH;
    const int E = in_sizes[2];
    const int nbins   = (N + BIN_NODES - 1) >> BIN_BITS;
    const int chunksz = (E + NCHUNK - 1) / NCHUNK;
    const int M2      = nbins * NCHUNK;
    const int* src = eidx;
    const int* dst = eidx + E;

    char* wp = (char*)d_ws;
    auto take = [&](size_t bytes) {
        char* p = wp;
        wp += (bytes + 63) & ~(size_t)63;
        return p;
    };
    int*   H      = (int*)take((size_t)M2 * sizeof(int));
    int*   blksum = (int*)take(4096 * sizeof(int));
    int*   ends   = (int*)take((size_t)nbins * KPB * sizeof(int));
    int*   csr    = (int*)take((size_t)E * sizeof(int));
    float* h      = (float*)take((size_t)N * HID_CH * sizeof(float));
    float* hW     = (float*)take((size_t)N * 16 * sizeof(float));
    float* hroot  = (float*)take((size_t)N * 2 * sizeof(float));
    int* be = (int*)h;   // alias: be dead before h's first write (l1 after bin_build)

    const int B = 256;
    const int nb = (M2 + 1023) / 1024;

    part_hist_kernel<<<NCHUNK, B, 0, stream>>>(dst, H, E, nbins, chunksz);
    scan_a_kernel<<<nb, 1024, 0, stream>>>(H, blksum, M2);
    scan_b_kernel<<<1, 64, 0, stream>>>(blksum, nb);
    scan_c_kernel<<<nb, 1024, 0, stream>>>(H, blksum, M2);
    part_scatter_kernel<<<NCHUNK, B, 0, stream>>>(src, dst, etype, H, be, E, nbins, chunksz);
    bin_build_kernel<<<nbins, B, 0, stream>>>(be, H, ends, csr, E, nbins);

    l1_fused_kernel<<<(N * 32 + B - 1) / B, B, 0, stream>>>(x, csr, ends, W1, root1, b1, h, N);
    hw_kernel<<<(N * 9 + B - 1) / B, B, 0, stream>>>(h, W2, root2, b2, hW, hroot, N);
    l2_finish_kernel<<<(N * 8 + B - 1) / B, B, 0, stream>>>(csr, ends, hW, hroot, out, N);
}